// Round 13
// baseline (341.519 us; speedup 1.0000x reference)
//
#include <hip/hip_runtime.h>
#include <hip/hip_bf16.h>
#include <math.h>

// Problem constants: B=2, S=2048, E=2048, HEADS=16, d=128
#define PB 2
#define PS 2048
#define PE 2048
#define PH 16
#define PD 128
#define PN_PROJ 6160   // 3*E + HEADS (fp32 weight layout)
#define PM 4096        // B*S
#define PQKV 6144      // 3*E — bf16 proj row length

typedef __attribute__((ext_vector_type(8))) short bf16x8;
typedef __attribute__((ext_vector_type(4))) float f32x4;

__device__ __forceinline__ void gload_lds16(const void* g, void* l) {
  __builtin_amdgcn_global_load_lds((const __attribute__((address_space(1))) void*)g,
                                   (__attribute__((address_space(3))) void*)l, 16, 0, 0);
}

// ---------------------------------------------------------------------------
// 8-phase 256x256 bf16 MFMA GEMM (m201-template port; GEMM1).
// 8 waves (2M x 4N), wave tile 128x64 (MF=8, NF=4), BK=64, LDS 128KB 2-dbuf.
// Per K-tile, 4 quadrant phases x 16 MFMA:
//   ph1: read av(m0-3)+bv01 (12 b128) | bar | lgkm0 | prio1 16MFMA prio0 | bar
//   ph2: read bv23 (4)               | bar | lgkm0 | prio1 16MFMA prio0 | bar
//   ph3: read av(m4-7) (8)           | bar | lgkm0 | prio1 16MFMA prio0 | bar
//   ph4: stage tile t+2 (8 gloads; buf fully read at ph3 bar) | 16MFMA (regs)
// vmcnt(8) ONCE per tile at loop top — tile t+1's loads never drained.
// XOR swizzle c^=row&7 on 128B rows (conflict-free, verified R9).
// ---------------------------------------------------------------------------
template <typename OutT>
__global__ __launch_bounds__(512, 1) void gemm_8p(
    const __hip_bfloat16* __restrict__ A, const __hip_bfloat16* __restrict__ Bt,
    OutT* __restrict__ C, int K, int lda, int ldb, int ldc, int nTilesX) {
  __shared__ __align__(16) char lds[131072];  // 2 buf x (A 32KB + B 32KB)

  const int tid = threadIdx.x;
  const int w = tid >> 6, lane = tid & 63;
  const int fq = lane >> 4, fr = lane & 15;
  const int wm = w >> 2, wn = w & 3;

  const int total = gridDim.x;
  const int swz = (blockIdx.x & 7) * (total >> 3) + (blockIdx.x >> 3);
  const int mBase = (swz / nTilesX) * 256;
  const int nBase = (swz % nTilesX) * 256;

  const int srow = tid >> 3, sc = tid & 7;  // 64 rows x 8 chunks per round

  auto stage = [&](int t) {
    char* base = lds + (size_t)(t & 1) * 65536;
#pragma unroll
    for (int l = 0; l < 4; ++l) {
      int row = l * 64 + srow;
      int cs = sc ^ (row & 7);
      gload_lds16(A + (size_t)(mBase + row) * lda + t * 64 + cs * 8,
                  base + l * 8192 + w * 1024);
    }
#pragma unroll
    for (int l = 0; l < 4; ++l) {
      int row = l * 64 + srow;
      int cs = sc ^ (row & 7);
      gload_lds16(Bt + (size_t)(nBase + row) * ldb + t * 64 + cs * 8,
                  base + 32768 + l * 8192 + w * 1024);
    }
  };

  f32x4 acc[8][4];
#pragma unroll
  for (int m = 0; m < 8; ++m)
#pragma unroll
    for (int n = 0; n < 4; ++n) acc[m][n] = (f32x4){0.f, 0.f, 0.f, 0.f};

  const int NT = K / 64;
  stage(0); stage(1);

#pragma unroll 1
  for (int t = 0; t < NT; ++t) {
    // tile t's loads landed; t+1's 8 stay in flight (never drain mid-loop)
    if (t + 1 < NT) asm volatile("s_waitcnt vmcnt(8)" ::: "memory");
    else            asm volatile("s_waitcnt vmcnt(0)" ::: "memory");
    __builtin_amdgcn_s_barrier();      // all waves' vmcnt passed; ph4-end bar
    __builtin_amdgcn_sched_barrier(0);

    const __hip_bfloat16* slA = (const __hip_bfloat16*)(lds + (size_t)(t & 1) * 65536);
    const __hip_bfloat16* slB = slA + 16384;

    // ---- ph1: quadrant (m0-3, n0-1); 12 ds_read_b128 ----
    bf16x8 avA[4][2], bv01[2][2], bv23[2][2], avB[4][2];
#pragma unroll
    for (int m = 0; m < 4; ++m)
#pragma unroll
      for (int kk = 0; kk < 2; ++kk) {
        int row = wm * 128 + m * 16 + fr;
        avA[m][kk] = *(const bf16x8*)&slA[row * 64 + (((kk * 4 + fq) ^ (row & 7)) * 8)];
      }
#pragma unroll
    for (int n = 0; n < 2; ++n)
#pragma unroll
      for (int kk = 0; kk < 2; ++kk) {
        int row = wn * 64 + n * 16 + fr;
        bv01[n][kk] = *(const bf16x8*)&slB[row * 64 + (((kk * 4 + fq) ^ (row & 7)) * 8)];
      }
    __builtin_amdgcn_s_barrier();
    asm volatile("s_waitcnt lgkmcnt(0)" ::: "memory");
    __builtin_amdgcn_sched_barrier(0);
    __builtin_amdgcn_s_setprio(1);
#pragma unroll
    for (int m = 0; m < 4; ++m)
#pragma unroll
      for (int n = 0; n < 2; ++n)
#pragma unroll
        for (int kk = 0; kk < 2; ++kk)
          acc[m][n] = __builtin_amdgcn_mfma_f32_16x16x32_bf16(avA[m][kk], bv01[n][kk], acc[m][n], 0, 0, 0);
    __builtin_amdgcn_s_setprio(0);
    __builtin_amdgcn_s_barrier();

    // ---- ph2: (m0-3, n2-3); 4 ds_read ----
#pragma unroll
    for (int n = 0; n < 2; ++n)
#pragma unroll
      for (int kk = 0; kk < 2; ++kk) {
        int row = wn * 64 + (2 + n) * 16 + fr;
        bv23[n][kk] = *(const bf16x8*)&slB[row * 64 + (((kk * 4 + fq) ^ (row & 7)) * 8)];
      }
    __builtin_amdgcn_s_barrier();
    asm volatile("s_waitcnt lgkmcnt(0)" ::: "memory");
    __builtin_amdgcn_sched_barrier(0);
    __builtin_amdgcn_s_setprio(1);
#pragma unroll
    for (int m = 0; m < 4; ++m)
#pragma unroll
      for (int n = 0; n < 2; ++n)
#pragma unroll
        for (int kk = 0; kk < 2; ++kk)
          acc[m][2 + n] = __builtin_amdgcn_mfma_f32_16x16x32_bf16(avA[m][kk], bv23[n][kk], acc[m][2 + n], 0, 0, 0);
    __builtin_amdgcn_s_setprio(0);
    __builtin_amdgcn_s_barrier();

    // ---- ph3: (m4-7, n2-3); 8 ds_read ----
#pragma unroll
    for (int m = 0; m < 4; ++m)
#pragma unroll
      for (int kk = 0; kk < 2; ++kk) {
        int row = wm * 128 + (4 + m) * 16 + fr;
        avB[m][kk] = *(const bf16x8*)&slA[row * 64 + (((kk * 4 + fq) ^ (row & 7)) * 8)];
      }
    __builtin_amdgcn_s_barrier();
    asm volatile("s_waitcnt lgkmcnt(0)" ::: "memory");
    __builtin_amdgcn_sched_barrier(0);
    __builtin_amdgcn_s_setprio(1);
#pragma unroll
    for (int m = 0; m < 4; ++m)
#pragma unroll
      for (int n = 0; n < 2; ++n)
#pragma unroll
        for (int kk = 0; kk < 2; ++kk)
          acc[4 + m][2 + n] = __builtin_amdgcn_mfma_f32_16x16x32_bf16(avB[m][kk], bv23[n][kk], acc[4 + m][2 + n], 0, 0, 0);
    __builtin_amdgcn_s_setprio(0);
    __builtin_amdgcn_s_barrier();      // buf[t&1] fully read by ALL waves

    // ---- ph4: stage t+2 into buf[t&1] (safe now); MFMA from regs only ----
    if (t + 2 < NT) stage(t + 2);
    __builtin_amdgcn_s_setprio(1);
#pragma unroll
    for (int m = 0; m < 4; ++m)
#pragma unroll
      for (int n = 0; n < 2; ++n)
#pragma unroll
        for (int kk = 0; kk < 2; ++kk)
          acc[4 + m][n] = __builtin_amdgcn_mfma_f32_16x16x32_bf16(avB[m][kk], bv01[n][kk], acc[4 + m][n], 0, 0, 0);
    __builtin_amdgcn_s_setprio(0);
    // loop-top barrier closes ph4
  }

  // epilogue: C/D layout col=lane&15, row=(lane>>4)*4+reg (m89-verified)
#pragma unroll
  for (int m = 0; m < 8; ++m) {
#pragma unroll
    for (int n = 0; n < 4; ++n) {
      int row0 = mBase + wm * 128 + m * 16 + fq * 4;
      int col = nBase + wn * 64 + n * 16 + fr;
#pragma unroll
      for (int j = 0; j < 4; ++j) {
        if constexpr (__is_same(OutT, float))
          C[(size_t)(row0 + j) * ldc + col] = acc[m][n][j];
        else
          C[(size_t)(row0 + j) * ldc + col] = __float2bfloat16(acc[m][n][j]);
      }
    }
  }
}

// ---------------------------------------------------------------------------
// 3-slot single-barrier GEMM (R12, validated; GEMM2).
// ---------------------------------------------------------------------------
template <int BM, int BN, int WM, int WN, typename OutT>
__global__ __launch_bounds__(512, 1) void gemm_cs3(
    const __hip_bfloat16* __restrict__ A, const __hip_bfloat16* __restrict__ Bt,
    OutT* __restrict__ C, int K, int lda, int ldb, int ldc, int nTilesX) {
  constexpr int MF = BM / WM / 16;
  constexpr int NF = BN / WN / 16;
  constexpr int SLOT = (BM + BN) * 64;
  constexpr int AL = BM / 64;
  constexpr int BL = BN / 64;
  constexpr int NLD = AL + BL;

  __shared__ __align__(16) __hip_bfloat16 lds[3 * SLOT];

  const int tid = threadIdx.x;
  const int w = tid >> 6, lane = tid & 63;
  const int fq = lane >> 4, fr = lane & 15;
  const int wm = w / WN, wn = w % WN;

  const int total = gridDim.x;
  const int swz = (blockIdx.x & 7) * (total >> 3) + (blockIdx.x >> 3);
  const int mBase = (swz / nTilesX) * BM;
  const int nBase = (swz % nTilesX) * BN;

  const int srow = tid >> 3, sc = tid & 7;

  auto stage = [&](int t) {
    char* base = (char*)lds + (size_t)(t % 3) * SLOT * 2;
#pragma unroll
    for (int l = 0; l < AL; ++l) {
      int row = l * 64 + srow;
      int cs = sc ^ (row & 7);
      gload_lds16(A + (size_t)(mBase + row) * lda + t * 64 + cs * 8,
                  base + l * 8192 + w * 1024);
    }
#pragma unroll
    for (int l = 0; l < BL; ++l) {
      int row = l * 64 + srow;
      int cs = sc ^ (row & 7);
      gload_lds16(Bt + (size_t)(nBase + row) * ldb + t * 64 + cs * 8,
                  base + BM * 128 + l * 8192 + w * 1024);
    }
  };

  f32x4 acc[MF][NF];
#pragma unroll
  for (int m = 0; m < MF; ++m)
#pragma unroll
    for (int n = 0; n < NF; ++n) acc[m][n] = (f32x4){0.f, 0.f, 0.f, 0.f};

  const int NT = K / 64;
  stage(0); stage(1);

#pragma unroll 1
  for (int t = 0; t < NT; ++t) {
    if (t + 1 < NT) asm volatile("s_waitcnt vmcnt(%0)" ::"i"(NLD) : "memory");
    else            asm volatile("s_waitcnt vmcnt(0)" ::: "memory");
    __builtin_amdgcn_s_barrier();
    __builtin_amdgcn_sched_barrier(0);
    if (t + 2 < NT) stage(t + 2);

    const __hip_bfloat16* sl = lds + (size_t)(t % 3) * SLOT;

#pragma unroll
    for (int kk = 0; kk < 2; ++kk) {
      bf16x8 av[MF], bv[NF];
#pragma unroll
      for (int m = 0; m < MF; ++m) {
        int row = wm * (BM / WM) + m * 16 + fr;
        av[m] = *(const bf16x8*)&sl[row * 64 + (((kk * 4 + fq) ^ (row & 7)) * 8)];
      }
#pragma unroll
      for (int n = 0; n < NF; ++n) {
        int row = wn * (BN / WN) + n * 16 + fr;
        bv[n] = *(const bf16x8*)&sl[BM * 64 + row * 64 + (((kk * 4 + fq) ^ (row & 7)) * 8)];
      }
      asm volatile("s_waitcnt lgkmcnt(0)" ::: "memory");
      __builtin_amdgcn_sched_barrier(0);
      __builtin_amdgcn_s_setprio(1);
#pragma unroll
      for (int m = 0; m < MF; ++m)
#pragma unroll
        for (int n = 0; n < NF; ++n)
          acc[m][n] = __builtin_amdgcn_mfma_f32_16x16x32_bf16(av[m], bv[n], acc[m][n], 0, 0, 0);
      __builtin_amdgcn_s_setprio(0);
    }
  }

#pragma unroll
  for (int m = 0; m < MF; ++m) {
#pragma unroll
    for (int n = 0; n < NF; ++n) {
      int row0 = mBase + wm * (BM / WM) + m * 16 + fq * 4;
      int col = nBase + wn * (BN / WN) + n * 16 + fr;
#pragma unroll
      for (int j = 0; j < 4; ++j) {
        if constexpr (__is_same(OutT, float))
          C[(size_t)(row0 + j) * ldc + col] = acc[m][n][j];
        else
          C[(size_t)(row0 + j) * ldc + col] = __float2bfloat16(acc[m][n][j]);
      }
    }
  }
}

// ---------------------------------------------------------------------------
__global__ __launch_bounds__(256) void cast_f32_bf16(const float* __restrict__ in,
                                                     __hip_bfloat16* __restrict__ out,
                                                     int n4) {
  int i = blockIdx.x * 256 + threadIdx.x;
  if (i >= n4) return;
  float4 v = ((const float4*)in)[i];
  union { __hip_bfloat16 h[4]; uint2 u; } pk;
  pk.h[0] = __float2bfloat16(v.x); pk.h[1] = __float2bfloat16(v.y);
  pk.h[2] = __float2bfloat16(v.z); pk.h[3] = __float2bfloat16(v.w);
  ((uint2*)out)[i] = pk.u;
}

// ---------------------------------------------------------------------------
__global__ __launch_bounds__(256) void transpose_cast(const float* __restrict__ W,
                                                      __hip_bfloat16* __restrict__ Wt,
                                                      int ldw, int ldt, int nOff) {
  __shared__ float t[32][33];
  int nb = blockIdx.x * 32, kb = blockIdx.y * 32;
  int tx = threadIdx.x & 31, ty = threadIdx.x >> 5;
#pragma unroll
  for (int i = 0; i < 4; ++i) {
    int k = ty + i * 8;
    t[k][tx] = W[(size_t)(kb + k) * ldw + nOff + nb + tx];
  }
  __syncthreads();
#pragma unroll
  for (int i = 0; i < 4; ++i) {
    int n = ty + i * 8;
    Wt[(size_t)(nb + n) * ldt + kb + tx] = __float2bfloat16(t[tx][n]);
  }
}

// ---------------------------------------------------------------------------
// Gate head from x (fp32): hgbuf[(b*H+h)*S+s] = tanh(x[bs,:] . W[:,3E+h])
// ---------------------------------------------------------------------------
__global__ __launch_bounds__(256) void hg_from_x(const float* __restrict__ x,
                                                 const float* __restrict__ W,
                                                 float* __restrict__ hgbuf) {
  int bs = blockIdx.x;
  int b = bs >> 11, s = bs & (PS - 1);
  __shared__ float xs[PE];
  __shared__ float red[16][17];
  const float* xr = x + (size_t)bs * PE;
  for (int i = threadIdx.x; i < PE / 4; i += 256)
    *(float4*)&xs[i * 4] = ((const float4*)xr)[i];
  __syncthreads();
  int h = threadIdx.x & 15, part = threadIdx.x >> 4;
  float acc = 0.f;
  for (int k = part * 128; k < part * 128 + 128; ++k)
    acc += xs[k] * W[(size_t)k * PN_PROJ + 3 * PE + h];
  red[part][h] = acc;
  __syncthreads();
  if (threadIdx.x < 16) {
    float sm = 0.f;
#pragma unroll
    for (int p = 0; p < 16; ++p) sm += red[p][threadIdx.x];
    hgbuf[(size_t)(b * PH + threadIdx.x) * PS + s] = tanhf(sm);
  }
}

// ---------------------------------------------------------------------------
// Kc scan on bf16 proj (fp32 accumulation), pre-scaled by 1/sqrt(E).
// ---------------------------------------------------------------------------
#define KC_SCALE 0.022097086912079608f  // 1/sqrt(2048)

__global__ __launch_bounds__(128) void kc_pass1(const __hip_bfloat16* __restrict__ proj,
                                                const float* __restrict__ hgbuf,
                                                float* __restrict__ csum) {
  int c = blockIdx.x & 15, bh = blockIdx.x >> 4;
  int h = bh & (PH - 1), b = bh >> 4;
  int d = threadIdx.x;
  __shared__ float hgs[128];
  hgs[d] = hgbuf[bh * PS + c * 128 + d];
  __syncthreads();
  const __hip_bfloat16* kbase = proj + (size_t)(b * PS) * PQKV + h * 384 + 128 + d;
  float acc = 0.f;
  int j0 = c * 128;
  for (int i = 0; i < 128; ++i) {
    int j = j0 + i;
    acc += (float)(j + 1) * hgs[i] * __bfloat162float(kbase[(size_t)j * PQKV]);
  }
  csum[blockIdx.x * 128 + d] = acc;
}

__global__ __launch_bounds__(128) void kc_pass2(__hip_bfloat16* __restrict__ proj,
                                                const float* __restrict__ hgbuf,
                                                const float* __restrict__ csum) {
  int c = blockIdx.x & 15, bh = blockIdx.x >> 4;
  int h = bh & (PH - 1), b = bh >> 4;
  int d = threadIdx.x;
  __shared__ float hgs[128];
  hgs[d] = hgbuf[bh * PS + c * 128 + d];
  __syncthreads();
  float acc = 0.f;
  for (int cc = 0; cc < c; ++cc) acc += csum[(bh * 16 + cc) * 128 + d];
  __hip_bfloat16* kbase = proj + (size_t)(b * PS) * PQKV + h * 384 + 128 + d;
  int j0 = c * 128;
  for (int i = 0; i < 128; ++i) {
    int j = j0 + i;
    acc += (float)(j + 1) * hgs[i] * __bfloat162float(kbase[(size_t)j * PQKV]);
    float t = (float)(j + 1);
    kbase[(size_t)j * PQKV] = __float2bfloat16(acc / (t * t) * KC_SCALE);
  }
}

// ---------------------------------------------------------------------------
// V^T pack: Vtp[bh][d][s]
// ---------------------------------------------------------------------------
__global__ __launch_bounds__(256) void vt_pack(const __hip_bfloat16* __restrict__ proj,
                                               __hip_bfloat16* __restrict__ Vtp) {
  int sc = blockIdx.x & 31, bh = blockIdx.x >> 5;
  int b = bh >> 4, h = bh & 15;
  int s0 = sc * 64;
  int tid = threadIdx.x;
  __shared__ __align__(16) __hip_bfloat16 Vlds[64][136];
  const __hip_bfloat16* src = proj + (size_t)(b * PS + s0) * PQKV + h * 384 + 256;
#pragma unroll
  for (int it = 0; it < 4; ++it) {
    int i = it * 256 + tid;
    int row = i >> 4, ch = i & 15;
    *(bf16x8*)&Vlds[row][ch * 8] = *(const bf16x8*)&src[(size_t)row * PQKV + ch * 8];
  }
  __syncthreads();
  int d = tid >> 1, half = tid & 1;
  __hip_bfloat16* dst = Vtp + ((size_t)bh * 128 + d) * PS + s0 + half * 32;
#pragma unroll
  for (int c8 = 0; c8 < 8; ++c8) {
    union { __hip_bfloat16 h4[4]; uint2 u; } pk;
#pragma unroll
    for (int k = 0; k < 4; ++k) pk.h4[k] = Vlds[half * 32 + c8 * 4 + k][d];
    *(uint2*)&dst[c8 * 4] = pk.u;
  }
}

// ---------------------------------------------------------------------------
// MFMA flash attention v3 (validated R6-R12): causal-balanced pairing,
// dbuf KV staging, swapped QK^T, defer-max, XOR-swizzled LDS.
// ---------------------------------------------------------------------------
__global__ __launch_bounds__(256) void attn_mfma(const __hip_bfloat16* __restrict__ proj,
                                                 const __hip_bfloat16* __restrict__ Vtp,
                                                 __hip_bfloat16* __restrict__ O) {
  const int bid = (blockIdx.x & 7) * 32 + (blockIdx.x >> 3);
  const int bh = bid >> 3, pk = bid & 7;
  const int b = bh >> 4, h = bh & 15;
  const int tid = threadIdx.x;
  const int w = tid >> 6, lane = tid & 63;
  const int fq = lane >> 4, fr = lane & 15;

  __shared__ __align__(16) char smem[120832];
  __hip_bfloat16* Psw = (__hip_bfloat16*)(smem + 65536) + w * 32 * 72;
  __hip_bfloat16* Os = (__hip_bfloat16*)(smem + 84480);

  const __hip_bfloat16* kb0 = proj + (size_t)(b * PS) * PQKV + h * 384 + 128;
  const __hip_bfloat16* vb0 = Vtp + (size_t)bh * 128 * PS;

  const int klr = lane >> 4, kc = lane & 15;
  const int vlr = lane >> 3, vc = lane & 7;

  auto stageKV = [&](int t, int bufi) {
    char* ksb = smem + bufi * 16384;
    char* vsb = smem + 32768 + bufi * 16384;
    const __hip_bfloat16* kb = kb0 + (size_t)(t * 64) * PQKV;
    const __hip_bfloat16* vb = vb0 + t * 64;
#pragma unroll
    for (int p = 0; p < 4; ++p) {
      int row = w * 16 + p * 4 + klr;
      int cs = kc ^ (row & 7);
      gload_lds16(kb + (size_t)row * PQKV + cs * 8, ksb + (w * 16 + p * 4) * 256);
    }
#pragma unroll
    for (int p = 0; p < 4; ++p) {
      int row = w * 32 + p * 8 + vlr;
      int cs = vc ^ (row & 7);
      gload_lds16(vb + (size_t)row * PS + cs * 8, vsb + (w * 32 + p * 8) * 128);
    }
  };

  stageKV(0, 0);
  int cur = 0;

#pragma unroll 1
  for (int phase = 0; phase < 2; ++phase) {
    const int qt = (phase == 0) ? pk : 15 - pk;
    const int nt = (qt + 1) * 2;
    const int q0 = qt * 128;
    const int qw = q0 + w * 32;

    const __hip_bfloat16* qbase = proj + (size_t)(b * PS + qw) * PQKV + h * 384;
    bf16x8 qf[2][4];
#pragma unroll
    for (int r2 = 0; r2 < 2; ++r2)
#pragma unroll
      for (int kk = 0; kk < 4; ++kk)
        qf[r2][kk] = *(const bf16x8*)&qbase[(size_t)(r2 * 16 + fr) * PQKV + kk * 32 + fq * 8];

    f32x4 oacc[2][8];
#pragma unroll
    for (int r2 = 0; r2 < 2; ++r2)
#pragma unroll
      for (int nd = 0; nd < 8; ++nd) oacc[r2][nd] = (f32x4){0.f, 0.f, 0.f, 0.f};
    float m_[2] = {-__builtin_inff(), -__builtin_inff()};
    float l_[2] = {0.f, 0.f};

#pragma unroll 1
    for (int kt = 0; kt < nt; ++kt) {
      const bool hasNext = (kt + 1 < nt) || (phase == 0);
      if (hasNext) stageKV((kt + 1 < nt) ? kt + 1 : 0, cur ^ 1);

      if (kt * 64 <= qw + 31) {
        const __hip_bfloat16* Ks = (const __hip_bfloat16*)(smem + cur * 16384);
        const __hip_bfloat16* Vts = (const __hip_bfloat16*)(smem + 32768 + cur * 16384);
        const bool diag = (kt * 64 + 63) > qw;

        f32x4 sacc[2][4];
#pragma unroll
        for (int r2 = 0; r2 < 2; ++r2)
#pragma unroll
          for (int n = 0; n < 4; ++n) sacc[r2][n] = (f32x4){0.f, 0.f, 0.f, 0.f};
#pragma unroll
        for (int kk = 0; kk < 4; ++kk) {
#pragma unroll
          for (int n = 0; n < 4; ++n) {
            bf16x8 kf = *(const bf16x8*)&Ks[(n * 16 + fr) * 128 + (((kk * 4 + fq) ^ (fr & 7)) * 8)];
            sacc[0][n] = __builtin_amdgcn_mfma_f32_16x16x32_bf16(kf, qf[0][kk], sacc[0][n], 0, 0, 0);
            sacc[1][n] = __builtin_amdgcn_mfma_f32_16x16x32_bf16(kf, qf[1][kk], sacc[1][n], 0, 0, 0);
          }
        }

#pragma unroll
        for (int r2 = 0; r2 < 2; ++r2) {
          const int qg = qw + r2 * 16 + fr;
          float sv[4][4];
#pragma unroll
          for (int n = 0; n < 4; ++n)
#pragma unroll
            for (int j = 0; j < 4; ++j) {
              float s = sacc[r2][n][j];
              if (diag && (kt * 64 + n * 16 + fq * 4 + j) > qg) s = -__builtin_inff();
              sv[n][j] = s;
            }
          float pmax = sv[0][0];
#pragma unroll
          for (int n = 0; n < 4; ++n)
#pragma unroll
            for (int j = 0; j < 4; ++j) pmax = fmaxf(pmax, sv[n][j]);
          pmax = fmaxf(pmax, __shfl_xor(pmax, 16, 64));
          pmax = fmaxf(pmax, __shfl_xor(pmax, 32, 64));

          const bool nof = __all(pmax <= m_[r2] + 8.f);
          const float mn = nof ? m_[r2] : fmaxf(m_[r2], pmax);
          float ps = 0.f;
#pragma unroll
          for (int n = 0; n < 4; ++n) {
            union { __hip_bfloat16 hh[4]; uint2 u; } pkk;
#pragma unroll
            for (int j = 0; j < 4; ++j) {
              float p = __expf(sv[n][j] - mn);
              ps += p;
              pkk.hh[j] = __float2bfloat16(p);
            }
            *(uint2*)&Psw[(r2 * 16 + fr) * 72 + n * 16 + fq * 4] = pkk.u;
          }
          ps += __shfl_xor(ps, 16, 64);
          ps += __shfl_xor(ps, 32, 64);

          if (!nof) {
            const float alpha = __expf(m_[r2] - mn);
            l_[r2] = l_[r2] * alpha + ps;
            m_[r2] = mn;
            float a0 = __shfl(alpha, fq * 4 + 0, 64);
            float a1 = __shfl(alpha, fq * 4 + 1, 64);
            float a2 = __shfl(alpha, fq * 4 + 2, 64);
            float a3 = __shfl(alpha, fq * 4 + 3, 64);
#pragma unroll
            for (int nd = 0; nd < 8; ++nd) {
              oacc[r2][nd][0] *= a0; oacc[r2][nd][1] *= a1;
              oacc[r2][nd][2] *= a2; oacc[r2][nd][3] *= a3;
            }
          } else {
            l_[r2] += ps;
          }
        }

#pragma unroll
        for (int kk2 = 0; kk2 < 2; ++kk2) {
          bf16x8 pa0 = *(const bf16x8*)&Psw[(0 * 16 + fr) * 72 + kk2 * 32 + fq * 8];
          bf16x8 pa1 = *(const bf16x8*)&Psw[(1 * 16 + fr) * 72 + kk2 * 32 + fq * 8];
#pragma unroll
          for (int nd = 0; nd < 8; ++nd) {
            bf16x8 vf = *(const bf16x8*)&Vts[(nd * 16 + fr) * 64 + (((kk2 * 4 + fq) ^ (fr & 7)) * 8)];
            oacc[0][nd] = __builtin_amdgcn_mfma_f32_16x16x32_bf16(pa0, vf, oacc[0][nd], 0, 0, 0);
            oacc[1][nd] = __builtin_amdgcn_mfma_f32_16x16x32_bf16(pa1, vf, oacc[1][nd], 0, 0, 0);
          }
        }
      }

      __syncthreads();
      cur ^= 1;
    }

    float i0 = 1.0f / l_[0], i1 = 1.0f / l_[1];
    float inv4[2][4];
#pragma unroll
    for (int j = 0; j < 4; ++j) {
      inv4[0][j] = __shfl(i0, fq * 4 + j, 64);
      inv4[1][j] = __shfl(i1, fq * 4 + j, 64);
    }
#pragma unroll
    for (int r2 = 0; r2 < 2; ++r2)
#pragma unroll
      for (int nd = 0; nd < 8; ++nd)
#pragma unroll
        for (int j = 0; j < 4; ++j)
          Os[(w * 32 + r2 * 16 + fq * 4 + j) * 136 + nd * 16 + fr] =
              __float2bfloat16(oacc[r2][nd][j] * inv4[r2][j]);
    __syncthreads();
#pragma unroll
    for (int it = 0; it < 8; ++it) {
      int i = it * 256 + tid;
      int row = i >> 4, ch = i & 15;
      *(bf16x8*)&O[(size_t)(b * PS + q0 + row) * PE + h * 128 + ch * 8] =
          *(const bf16x8*)&Os[row * 136 + ch * 8];
    }
  }
}

// ---------------------------------------------------------------------------
extern "C" void kernel_launch(void* const* d_in, const int* in_sizes, int n_in,
                              void* d_out, int out_size, void* d_ws, size_t ws_size,
                              hipStream_t stream) {
  const float* x     = (const float*)d_in[0];
  const float* Wqkvh = (const float*)d_in[1];
  const float* Wout  = (const float*)d_in[2];
  float* out = (float*)d_out;

  char* wsb = (char*)d_ws;
  __hip_bfloat16* proj = (__hip_bfloat16*)wsb;          // [4096][6144] bf16
  wsb += (size_t)PM * PQKV * 2;
  __hip_bfloat16* xb = (__hip_bfloat16*)wsb;            // reused as attn out
  wsb += (size_t)PM * PE * 2;
  __hip_bfloat16* Wq_t = (__hip_bfloat16*)wsb;
  wsb += (size_t)PQKV * PE * 2;
  __hip_bfloat16* Wout_t = (__hip_bfloat16*)wsb;
  wsb += (size_t)PE * PE * 2;
  __hip_bfloat16* Vtp = (__hip_bfloat16*)wsb;           // [32][128][2048]
  wsb += (size_t)PB * PH * PD * PS * 2;
  float* hgbuf = (float*)wsb;
  wsb += (size_t)PB * PH * PS * 4;
  float* csum = (float*)wsb;

  // 0) casts / weight transposes
  cast_f32_bf16<<<(PM * PE / 4 + 255) / 256, 256, 0, stream>>>(x, xb, PM * PE / 4);
  transpose_cast<<<dim3(PQKV / 32, PE / 32), 256, 0, stream>>>(Wqkvh, Wq_t, PN_PROJ, PE, 0);
  transpose_cast<<<dim3(PE / 32, PE / 32), 256, 0, stream>>>(Wout, Wout_t, PE, PE, 0);

  // 1) proj = x @ W_qkvh[:, :6144] (bf16 out) — 8-phase 256x256 template,
  //    grid 384 (1.5 rounds, accepted)
  gemm_8p<__hip_bfloat16>
      <<<dim3((PM / 256) * (PQKV / 256)), 512, 0, stream>>>(
          xb, Wq_t, proj, PE, PE, PE, PQKV, PQKV / 256);

  // 2) gate head + causal weighted cumsum (bf16 in place, pre-scaled)
  hg_from_x<<<PM, 256, 0, stream>>>(x, Wqkvh, hgbuf);
  kc_pass1<<<PB * PH * 16, 128, 0, stream>>>(proj, hgbuf, csum);
  kc_pass2<<<PB * PH * 16, 128, 0, stream>>>(proj, hgbuf, csum);

  // 3) V^T pack + MFMA flash attention -> xb
  vt_pack<<<PB * PH * 32, 256, 0, stream>>>(proj, Vtp);
  __hip_bfloat16* Ob = xb;
  attn_mfma<<<PB * PH * 8, 256, 0, stream>>>(proj, Vtp, Ob);

  // 4) out = Oattn @ W_out (fp32 out) — 3-slot single-barrier, grid 256
  gemm_cs3<128, 256, 2, 4, float>
      <<<dim3((PM / 128) * (PE / 256)), 512, 0, stream>>>(
          Ob, Wout_t, out, PE, PE, PE, PE, PE / 256);
}

// Round 14
// 313.245 us; speedup vs baseline: 1.0903x; 1.0903x over previous
//
#include <hip/hip_runtime.h>
#include <hip/hip_bf16.h>
#include <math.h>

// Problem constants: B=2, S=2048, E=2048, HEADS=16, d=128
#define PB 2
#define PS 2048
#define PE 2048
#define PH 16
#define PD 128
#define PN_PROJ 6160   // 3*E + HEADS (fp32 weight layout)
#define PM 4096        // B*S

typedef __attribute__((ext_vector_type(8))) short bf16x8;
typedef __attribute__((ext_vector_type(4))) float f32x4;

__device__ __forceinline__ void gload_lds16(const void* g, void* l) {
  __builtin_amdgcn_global_load_lds((const __attribute__((address_space(1))) void*)g,
                                   (__attribute__((address_space(3))) void*)l, 16, 0, 0);
}

// ---------------------------------------------------------------------------
// GEMM1: R9-exact cs2 schedule (proven 898 TF, 0 conflicts), 128x384 tile
// (BN=384 = exactly one head), epilogue writes PACKED Qp/Kp/Vp[bh][s][d].
// 2 LDS slots; 128B rows, 8-position XOR swizzle (c ^= row&7).
// Per K-tile: vmcnt(NLD); barrier; {ds_read kk0; lgkm(0); MFMA kk0};
// {ds_read kk1; lgkm(0); barrier; stage(t+2); MFMA kk1}.
// 8 waves (512 thr) — do NOT exceed 8 waves/block (R11: 16-wave spilled).
// ---------------------------------------------------------------------------
__global__ __launch_bounds__(512, 1) void gemm_qkv(
    const __hip_bfloat16* __restrict__ A, const __hip_bfloat16* __restrict__ Bt,
    __hip_bfloat16* __restrict__ Qp, __hip_bfloat16* __restrict__ Kp,
    __hip_bfloat16* __restrict__ Vp, int K, int nTilesX) {
  constexpr int BM = 128, BN = 384, WM = 2, WN = 4;
  constexpr int MF = BM / WM / 16;   // 4
  constexpr int NF = BN / WN / 16;   // 6
  constexpr int SLOT = (BM + BN) * 64;
  constexpr int AL = BM / 64;
  constexpr int BL = BN / 64;
  constexpr int NLD = AL + BL;

  __shared__ __align__(16) __hip_bfloat16 lds[2 * SLOT];

  const int tid = threadIdx.x;
  const int w = tid >> 6, lane = tid & 63;
  const int fq = lane >> 4, fr = lane & 15;
  const int wm = w / WN, wn = w % WN;

  const int total = gridDim.x;
  const int swz = (blockIdx.x & 7) * (total >> 3) + (blockIdx.x >> 3);
  const int mBase = (swz / nTilesX) * BM;
  const int h = swz % nTilesX;       // head (BN == 384 == one head)
  const int nBase = h * BN;

  const int srow = tid >> 3, sc = tid & 7;

  auto stage = [&](int t) {
    char* base = (char*)lds + (size_t)(t & 1) * SLOT * 2;
#pragma unroll
    for (int l = 0; l < AL; ++l) {
      int row = l * 64 + srow;
      int cs = sc ^ (row & 7);
      gload_lds16(A + (size_t)(mBase + row) * K + t * 64 + cs * 8,
                  base + l * 8192 + w * 1024);
    }
#pragma unroll
    for (int l = 0; l < BL; ++l) {
      int row = l * 64 + srow;
      int cs = sc ^ (row & 7);
      gload_lds16(Bt + (size_t)(nBase + row) * K + t * 64 + cs * 8,
                  base + BM * 128 + l * 8192 + w * 1024);
    }
  };

  f32x4 acc[MF][NF];
#pragma unroll
  for (int m = 0; m < MF; ++m)
#pragma unroll
    for (int n = 0; n < NF; ++n) acc[m][n] = (f32x4){0.f, 0.f, 0.f, 0.f};

  const int NT = K / 64;
  stage(0); stage(1);

#pragma unroll 1
  for (int t = 0; t < NT; ++t) {
    if (t + 1 < NT) asm volatile("s_waitcnt vmcnt(%0)" ::"i"(NLD) : "memory");
    else            asm volatile("s_waitcnt vmcnt(0)" ::: "memory");
    __builtin_amdgcn_s_barrier();
    __builtin_amdgcn_sched_barrier(0);

    const __hip_bfloat16* sl = lds + (size_t)(t & 1) * SLOT;

    // ---- kk = 0 ----
    bf16x8 av[MF], bv[NF];
#pragma unroll
    for (int m = 0; m < MF; ++m) {
      int row = wm * (BM / WM) + m * 16 + fr;
      av[m] = *(const bf16x8*)&sl[row * 64 + ((fq ^ (row & 7)) * 8)];
    }
#pragma unroll
    for (int n = 0; n < NF; ++n) {
      int row = wn * (BN / WN) + n * 16 + fr;
      bv[n] = *(const bf16x8*)&sl[BM * 64 + row * 64 + ((fq ^ (row & 7)) * 8)];
    }
    asm volatile("s_waitcnt lgkmcnt(0)" ::: "memory");
    __builtin_amdgcn_sched_barrier(0);
    __builtin_amdgcn_s_setprio(1);
#pragma unroll
    for (int m = 0; m < MF; ++m)
#pragma unroll
      for (int n = 0; n < NF; ++n)
        acc[m][n] = __builtin_amdgcn_mfma_f32_16x16x32_bf16(av[m], bv[n], acc[m][n], 0, 0, 0);
    __builtin_amdgcn_s_setprio(0);

    // ---- kk = 1 ----
#pragma unroll
    for (int m = 0; m < MF; ++m) {
      int row = wm * (BM / WM) + m * 16 + fr;
      av[m] = *(const bf16x8*)&sl[row * 64 + (((4 + fq) ^ (row & 7)) * 8)];
    }
#pragma unroll
    for (int n = 0; n < NF; ++n) {
      int row = wn * (BN / WN) + n * 16 + fr;
      bv[n] = *(const bf16x8*)&sl[BM * 64 + row * 64 + (((4 + fq) ^ (row & 7)) * 8)];
    }
    asm volatile("s_waitcnt lgkmcnt(0)" ::: "memory");
    __builtin_amdgcn_s_barrier();
    __builtin_amdgcn_sched_barrier(0);
    if (t + 2 < NT) stage(t + 2);
    __builtin_amdgcn_s_setprio(1);
#pragma unroll
    for (int m = 0; m < MF; ++m)
#pragma unroll
      for (int n = 0; n < NF; ++n)
        acc[m][n] = __builtin_amdgcn_mfma_f32_16x16x32_bf16(av[m], bv[n], acc[m][n], 0, 0, 0);
    __builtin_amdgcn_s_setprio(0);
  }

  // epilogue: packed QKV write. col_local -> which = col/128, d = col%128.
  // 16 consecutive fr lanes share `which` (fragment starts are 16-multiples).
#pragma unroll
  for (int m = 0; m < MF; ++m) {
#pragma unroll
    for (int n = 0; n < NF; ++n) {
      int row0 = mBase + wm * (BM / WM) + m * 16 + fq * 4;
      int colL = wn * (BN / WN) + n * 16 + fr;
      int which = colL >> 7;
      int d = colL & 127;
      __hip_bfloat16* dst = which == 0 ? Qp : (which == 1 ? Kp : Vp);
#pragma unroll
      for (int j = 0; j < 4; ++j) {
        int row = row0 + j;
        int b = row >> 11, s = row & (PS - 1);
        dst[(((size_t)(b * PH + h)) * PS + s) * PD + d] = __float2bfloat16(acc[m][n][j]);
      }
    }
  }
}

// ---------------------------------------------------------------------------
// 3-slot single-barrier GEMM (R12, validated; GEMM2).
// ---------------------------------------------------------------------------
template <int BM, int BN, int WM, int WN, typename OutT>
__global__ __launch_bounds__(512, 1) void gemm_cs3(
    const __hip_bfloat16* __restrict__ A, const __hip_bfloat16* __restrict__ Bt,
    OutT* __restrict__ C, int K, int lda, int ldb, int ldc, int nTilesX) {
  constexpr int MF = BM / WM / 16;
  constexpr int NF = BN / WN / 16;
  constexpr int SLOT = (BM + BN) * 64;
  constexpr int AL = BM / 64;
  constexpr int BL = BN / 64;
  constexpr int NLD = AL + BL;

  __shared__ __align__(16) __hip_bfloat16 lds[3 * SLOT];

  const int tid = threadIdx.x;
  const int w = tid >> 6, lane = tid & 63;
  const int fq = lane >> 4, fr = lane & 15;
  const int wm = w / WN, wn = w % WN;

  const int total = gridDim.x;
  const int swz = (blockIdx.x & 7) * (total >> 3) + (blockIdx.x >> 3);
  const int mBase = (swz / nTilesX) * BM;
  const int nBase = (swz % nTilesX) * BN;

  const int srow = tid >> 3, sc = tid & 7;

  auto stage = [&](int t) {
    char* base = (char*)lds + (size_t)(t % 3) * SLOT * 2;
#pragma unroll
    for (int l = 0; l < AL; ++l) {
      int row = l * 64 + srow;
      int cs = sc ^ (row & 7);
      gload_lds16(A + (size_t)(mBase + row) * lda + t * 64 + cs * 8,
                  base + l * 8192 + w * 1024);
    }
#pragma unroll
    for (int l = 0; l < BL; ++l) {
      int row = l * 64 + srow;
      int cs = sc ^ (row & 7);
      gload_lds16(Bt + (size_t)(nBase + row) * ldb + t * 64 + cs * 8,
                  base + BM * 128 + l * 8192 + w * 1024);
    }
  };

  f32x4 acc[MF][NF];
#pragma unroll
  for (int m = 0; m < MF; ++m)
#pragma unroll
    for (int n = 0; n < NF; ++n) acc[m][n] = (f32x4){0.f, 0.f, 0.f, 0.f};

  const int NT = K / 64;
  stage(0); stage(1);

#pragma unroll 1
  for (int t = 0; t < NT; ++t) {
    if (t + 1 < NT) asm volatile("s_waitcnt vmcnt(%0)" ::"i"(NLD) : "memory");
    else            asm volatile("s_waitcnt vmcnt(0)" ::: "memory");
    __builtin_amdgcn_s_barrier();
    __builtin_amdgcn_sched_barrier(0);
    if (t + 2 < NT) stage(t + 2);

    const __hip_bfloat16* sl = lds + (size_t)(t % 3) * SLOT;

#pragma unroll
    for (int kk = 0; kk < 2; ++kk) {
      bf16x8 av[MF], bv[NF];
#pragma unroll
      for (int m = 0; m < MF; ++m) {
        int row = wm * (BM / WM) + m * 16 + fr;
        av[m] = *(const bf16x8*)&sl[row * 64 + (((kk * 4 + fq) ^ (row & 7)) * 8)];
      }
#pragma unroll
      for (int n = 0; n < NF; ++n) {
        int row = wn * (BN / WN) + n * 16 + fr;
        bv[n] = *(const bf16x8*)&sl[BM * 64 + row * 64 + (((kk * 4 + fq) ^ (row & 7)) * 8)];
      }
      asm volatile("s_waitcnt lgkmcnt(0)" ::: "memory");
      __builtin_amdgcn_sched_barrier(0);
      __builtin_amdgcn_s_setprio(1);
#pragma unroll
      for (int m = 0; m < MF; ++m)
#pragma unroll
        for (int n = 0; n < NF; ++n)
          acc[m][n] = __builtin_amdgcn_mfma_f32_16x16x32_bf16(av[m], bv[n], acc[m][n], 0, 0, 0);
      __builtin_amdgcn_s_setprio(0);
    }
  }

#pragma unroll
  for (int m = 0; m < MF; ++m) {
#pragma unroll
    for (int n = 0; n < NF; ++n) {
      int row0 = mBase + wm * (BM / WM) + m * 16 + fq * 4;
      int col = nBase + wn * (BN / WN) + n * 16 + fr;
#pragma unroll
      for (int j = 0; j < 4; ++j) {
        if constexpr (__is_same(OutT, float))
          C[(size_t)(row0 + j) * ldc + col] = acc[m][n][j];
        else
          C[(size_t)(row0 + j) * ldc + col] = __float2bfloat16(acc[m][n][j]);
      }
    }
  }
}

// ---------------------------------------------------------------------------
__global__ __launch_bounds__(256) void transpose_cast(const float* __restrict__ W,
                                                      __hip_bfloat16* __restrict__ Wt,
                                                      int ldw, int ldt, int nOff) {
  __shared__ float t[32][33];
  int nb = blockIdx.x * 32, kb = blockIdx.y * 32;
  int tx = threadIdx.x & 31, ty = threadIdx.x >> 5;
#pragma unroll
  for (int i = 0; i < 4; ++i) {
    int k = ty + i * 8;
    t[k][tx] = W[(size_t)(kb + k) * ldw + nOff + nb + tx];
  }
  __syncthreads();
#pragma unroll
  for (int i = 0; i < 4; ++i) {
    int n = ty + i * 8;
    Wt[(size_t)(nb + n) * ldt + kb + tx] = __float2bfloat16(t[tx][n]);
  }
}

// ---------------------------------------------------------------------------
// Gate head + x cast (fused): hgbuf[(b*H+h)*S+s] = tanh(x[bs,:].W[:,3E+h]);
// xb[bs,:] = bf16(x[bs,:]) emitted from the staged LDS row.
// ---------------------------------------------------------------------------
__global__ __launch_bounds__(256) void hg_from_x(const float* __restrict__ x,
                                                 const float* __restrict__ W,
                                                 float* __restrict__ hgbuf,
                                                 __hip_bfloat16* __restrict__ xb) {
  int bs = blockIdx.x;
  int b = bs >> 11, s = bs & (PS - 1);
  __shared__ float xs[PE];
  __shared__ float red[16][17];
  const float* xr = x + (size_t)bs * PE;
  for (int i = threadIdx.x; i < PE / 4; i += 256)
    *(float4*)&xs[i * 4] = ((const float4*)xr)[i];
  __syncthreads();
  // fused bf16 cast of the x row (8 elems/thread)
  {
    union { __hip_bfloat16 hh[8]; bf16x8 v; } pk;
#pragma unroll
    for (int k = 0; k < 8; ++k) pk.hh[k] = __float2bfloat16(xs[threadIdx.x * 8 + k]);
    *(bf16x8*)&xb[(size_t)bs * PE + threadIdx.x * 8] = pk.v;
  }
  int h = threadIdx.x & 15, part = threadIdx.x >> 4;
  float acc = 0.f;
  for (int k = part * 128; k < part * 128 + 128; ++k)
    acc += xs[k] * W[(size_t)k * PN_PROJ + 3 * PE + h];
  red[part][h] = acc;
  __syncthreads();
  if (threadIdx.x < 16) {
    float sm = 0.f;
#pragma unroll
    for (int p = 0; p < 16; ++p) sm += red[p][threadIdx.x];
    hgbuf[(size_t)(b * PH + threadIdx.x) * PS + s] = tanhf(sm);
  }
}

// ---------------------------------------------------------------------------
// Kc scan on PACKED Kp[bh][s][d] (coalesced 256B row reads), fp32 accum,
// written back pre-scaled by 1/sqrt(E).
// ---------------------------------------------------------------------------
#define KC_SCALE 0.022097086912079608f  // 1/sqrt(2048)

__global__ __launch_bounds__(128) void kc_pass1(const __hip_bfloat16* __restrict__ Kp,
                                                const float* __restrict__ hgbuf,
                                                float* __restrict__ csum) {
  int c = blockIdx.x & 15, bh = blockIdx.x >> 4;
  int d = threadIdx.x;
  __shared__ float hgs[128];
  hgs[d] = hgbuf[(size_t)bh * PS + c * 128 + d];
  __syncthreads();
  const __hip_bfloat16* kb = Kp + ((size_t)bh * PS + c * 128) * PD + d;
  float acc = 0.f;
  int j0 = c * 128;
  for (int i = 0; i < 128; ++i)
    acc += (float)(j0 + i + 1) * hgs[i] * __bfloat162float(kb[(size_t)i * PD]);
  csum[blockIdx.x * 128 + d] = acc;
}

__global__ __launch_bounds__(128) void kc_pass2(__hip_bfloat16* __restrict__ Kp,
                                                const float* __restrict__ hgbuf,
                                                const float* __restrict__ csum) {
  int c = blockIdx.x & 15, bh = blockIdx.x >> 4;
  int d = threadIdx.x;
  __shared__ float hgs[128];
  hgs[d] = hgbuf[(size_t)bh * PS + c * 128 + d];
  __syncthreads();
  float acc = 0.f;
  for (int cc = 0; cc < c; ++cc) acc += csum[(bh * 16 + cc) * 128 + d];
  __hip_bfloat16* kb = Kp + ((size_t)bh * PS + c * 128) * PD + d;
  int j0 = c * 128;
  for (int i = 0; i < 128; ++i) {
    float t = (float)(j0 + i + 1);
    acc += t * hgs[i] * __bfloat162float(kb[(size_t)i * PD]);
    kb[(size_t)i * PD] = __float2bfloat16(acc / (t * t) * KC_SCALE);
  }
}

// ---------------------------------------------------------------------------
// V^T pack from packed Vp[bh][s][d]: Vtp[bh][d][s]
// ---------------------------------------------------------------------------
__global__ __launch_bounds__(256) void vt_pack(const __hip_bfloat16* __restrict__ Vp,
                                               __hip_bfloat16* __restrict__ Vtp) {
  int sc = blockIdx.x & 31, bh = blockIdx.x >> 5;
  int s0 = sc * 64;
  int tid = threadIdx.x;
  __shared__ __align__(16) __hip_bfloat16 Vlds[64][136];
  const __hip_bfloat16* src = Vp + ((size_t)bh * PS + s0) * PD;
#pragma unroll
  for (int it = 0; it < 4; ++it) {
    int i = it * 256 + tid;
    int row = i >> 4, ch = i & 15;
    *(bf16x8*)&Vlds[row][ch * 8] = *(const bf16x8*)&src[(size_t)row * PD + ch * 8];
  }
  __syncthreads();
  int d = tid >> 1, half = tid & 1;
  __hip_bfloat16* dst = Vtp + ((size_t)bh * PD + d) * PS + s0 + half * 32;
#pragma unroll
  for (int c8 = 0; c8 < 8; ++c8) {
    union { __hip_bfloat16 h4[4]; uint2 u; } pk;
#pragma unroll
    for (int k = 0; k < 4; ++k) pk.h4[k] = Vlds[half * 32 + c8 * 4 + k][d];
    *(uint2*)&dst[c8 * 4] = pk.u;
  }
}

// ---------------------------------------------------------------------------
// MFMA flash attention v3 (validated R6-R13), now reading packed Qp/Kp:
// causal-balanced pairing, dbuf KV staging, swapped QK^T, defer-max,
// XOR-swizzled LDS.
// ---------------------------------------------------------------------------
__global__ __launch_bounds__(256) void attn_mfma(const __hip_bfloat16* __restrict__ Qp,
                                                 const __hip_bfloat16* __restrict__ Kp,
                                                 const __hip_bfloat16* __restrict__ Vtp,
                                                 __hip_bfloat16* __restrict__ O) {
  const int bid = (blockIdx.x & 7) * 32 + (blockIdx.x >> 3);
  const int bh = bid >> 3, pk = bid & 7;
  const int b = bh >> 4, h = bh & 15;
  const int tid = threadIdx.x;
  const int w = tid >> 6, lane = tid & 63;
  const int fq = lane >> 4, fr = lane & 15;

  __shared__ __align__(16) char smem[120832];
  __hip_bfloat16* Psw = (__hip_bfloat16*)(smem + 65536) + w * 32 * 72;
  __hip_bfloat16* Os = (__hip_bfloat16*)(smem + 84480);

  const __hip_bfloat16* kb0 = Kp + (size_t)bh * PS * PD;
  const __hip_bfloat16* vb0 = Vtp + (size_t)bh * PD * PS;

  const int klr = lane >> 4, kc = lane & 15;
  const int vlr = lane >> 3, vc = lane & 7;

  auto stageKV = [&](int t, int bufi) {
    char* ksb = smem + bufi * 16384;
    char* vsb = smem + 32768 + bufi * 16384;
    const __hip_bfloat16* kb = kb0 + (size_t)(t * 64) * PD;
    const __hip_bfloat16* vb = vb0 + t * 64;
#pragma unroll
    for (int p = 0; p < 4; ++p) {
      int row = w * 16 + p * 4 + klr;
      int cs = kc ^ (row & 7);
      gload_lds16(kb + (size_t)row * PD + cs * 8, ksb + (w * 16 + p * 4) * 256);
    }
#pragma unroll
    for (int p = 0; p < 4; ++p) {
      int row = w * 32 + p * 8 + vlr;
      int cs = vc ^ (row & 7);
      gload_lds16(vb + (size_t)row * PS + cs * 8, vsb + (w * 32 + p * 8) * 128);
    }
  };

  stageKV(0, 0);
  int cur = 0;

#pragma unroll 1
  for (int phase = 0; phase < 2; ++phase) {
    const int qt = (phase == 0) ? pk : 15 - pk;
    const int nt = (qt + 1) * 2;
    const int q0 = qt * 128;
    const int qw = q0 + w * 32;

    const __hip_bfloat16* qbase = Qp + ((size_t)bh * PS + qw) * PD;
    bf16x8 qf[2][4];
#pragma unroll
    for (int r2 = 0; r2 < 2; ++r2)
#pragma unroll
      for (int kk = 0; kk < 4; ++kk)
        qf[r2][kk] = *(const bf16x8*)&qbase[(size_t)(r2 * 16 + fr) * PD + kk * 32 + fq * 8];

    f32x4 oacc[2][8];
#pragma unroll
    for (int r2 = 0; r2 < 2; ++r2)
#pragma unroll
      for (int nd = 0; nd < 8; ++nd) oacc[r2][nd] = (f32x4){0.f, 0.f, 0.f, 0.f};
    float m_[2] = {-__builtin_inff(), -__builtin_inff()};
    float l_[2] = {0.f, 0.f};

#pragma unroll 1
    for (int kt = 0; kt < nt; ++kt) {
      const bool hasNext = (kt + 1 < nt) || (phase == 0);
      if (hasNext) stageKV((kt + 1 < nt) ? kt + 1 : 0, cur ^ 1);

      if (kt * 64 <= qw + 31) {
        const __hip_bfloat16* Ks = (const __hip_bfloat16*)(smem + cur * 16384);
        const __hip_bfloat16* Vts = (const __hip_bfloat16*)(smem + 32768 + cur * 16384);
        const bool diag = (kt * 64 + 63) > qw;

        f32x4 sacc[2][4];
#pragma unroll
        for (int r2 = 0; r2 < 2; ++r2)
#pragma unroll
          for (int n = 0; n < 4; ++n) sacc[r2][n] = (f32x4){0.f, 0.f, 0.f, 0.f};
#pragma unroll
        for (int kk = 0; kk < 4; ++kk) {
#pragma unroll
          for (int n = 0; n < 4; ++n) {
            bf16x8 kf = *(const bf16x8*)&Ks[(n * 16 + fr) * 128 + (((kk * 4 + fq) ^ (fr & 7)) * 8)];
            sacc[0][n] = __builtin_amdgcn_mfma_f32_16x16x32_bf16(kf, qf[0][kk], sacc[0][n], 0, 0, 0);
            sacc[1][n] = __builtin_amdgcn_mfma_f32_16x16x32_bf16(kf, qf[1][kk], sacc[1][n], 0, 0, 0);
          }
        }

#pragma unroll
        for (int r2 = 0; r2 < 2; ++r2) {
          const int qg = qw + r2 * 16 + fr;
          float sv[4][4];
#pragma unroll
          for (int n = 0; n < 4; ++n)
#pragma unroll
            for (int j = 0; j < 4; ++j) {
              float s = sacc[r2][n][j];
              if (diag && (kt * 64 + n * 16 + fq * 4 + j) > qg) s = -__builtin_inff();
              sv[n][j] = s;
            }
          float pmax = sv[0][0];
#pragma unroll
          for (int n = 0; n < 4; ++n)
#pragma unroll
            for (int j = 0; j < 4; ++j) pmax = fmaxf(pmax, sv[n][j]);
          pmax = fmaxf(pmax, __shfl_xor(pmax, 16, 64));
          pmax = fmaxf(pmax, __shfl_xor(pmax, 32, 64));

          const bool nof = __all(pmax <= m_[r2] + 8.f);
          const float mn = nof ? m_[r2] : fmaxf(m_[r2], pmax);
          float ps = 0.f;
#pragma unroll
          for (int n = 0; n < 4; ++n) {
            union { __hip_bfloat16 hh[4]; uint2 u; } pkk;
#pragma unroll
            for (int j = 0; j < 4; ++j) {
              float p = __expf(sv[n][j] - mn);
              ps += p;
              pkk.hh[j] = __float2bfloat16(p);
            }
            *(uint2*)&Psw[(r2 * 16 + fr) * 72 + n * 16 + fq * 4] = pkk.u;
          }
          ps += __shfl_xor(ps, 16, 64);
          ps += __shfl_xor(ps, 32, 64);

          if (!nof) {
            const float alpha = __expf(m_[r2] - mn);
            l_[r2] = l_[r2] * alpha + ps;
            m_[r2] = mn;
            float a0 = __shfl(alpha, fq * 4 + 0, 64);
            float a1 = __shfl(alpha, fq * 4 + 1, 64);
            float a2 = __shfl(alpha, fq * 4 + 2, 64);
            float a3 = __shfl(alpha, fq * 4 + 3, 64);
#pragma unroll
            for (int nd = 0; nd < 8; ++nd) {
              oacc[r2][nd][0] *= a0; oacc[r2][nd][1] *= a1;
              oacc[r2][nd][2] *= a2; oacc[r2][nd][3] *= a3;
            }
          } else {
            l_[r2] += ps;
          }
        }

#pragma unroll
        for (int kk2 = 0; kk2 < 2; ++kk2) {
          bf16x8 pa0 = *(const bf16x8*)&Psw[(0 * 16 + fr) * 72 + kk2 * 32 + fq * 8];
          bf16x8 pa1 = *(const bf16x8*)&Psw[(1 * 16 + fr) * 72 + kk2 * 32 + fq * 8];
#pragma unroll
          for (int nd = 0; nd < 8; ++nd) {
            bf16x8 vf = *(const bf16x8*)&Vts[(nd * 16 + fr) * 64 + (((kk2 * 4 + fq) ^ (fr & 7)) * 8)];
            oacc[0][nd] = __builtin_amdgcn_mfma_f32_16x16x32_bf16(pa0, vf, oacc[0][nd], 0, 0, 0);
            oacc[1][nd] = __builtin_amdgcn_mfma_f32_16x16x32_bf16(pa1, vf, oacc[1][nd], 0, 0, 0);
          }
        }
      }

      __syncthreads();
      cur ^= 1;
    }

    float i0 = 1.0f / l_[0], i1 = 1.0f / l_[1];
    float inv4[2][4];
#pragma unroll
    for (int j = 0; j < 4; ++j) {
      inv4[0][j] = __shfl(i0, fq * 4 + j, 64);
      inv4[1][j] = __shfl(i1, fq * 4 + j, 64);
    }
#pragma unroll
    for (int r2 = 0; r2 < 2; ++r2)
#pragma unroll
      for (int nd = 0; nd < 8; ++nd)
#pragma unroll
        for (int j = 0; j < 4; ++j)
          Os[(w * 32 + r2 * 16 + fq * 4 + j) * 136 + nd * 16 + fr] =
              __float2bfloat16(oacc[r2][nd][j] * inv4[r2][j]);
    __syncthreads();
#pragma unroll
    for (int it = 0; it < 8; ++it) {
      int i = it * 256 + tid;
      int row = i >> 4, ch = i & 15;
      *(bf16x8*)&O[(size_t)(b * PS + q0 + row) * PE + h * 128 + ch * 8] =
          *(const bf16x8*)&Os[row * 136 + ch * 8];
    }
  }
}

// ---------------------------------------------------------------------------
extern "C" void kernel_launch(void* const* d_in, const int* in_sizes, int n_in,
                              void* d_out, int out_size, void* d_ws, size_t ws_size,
                              hipStream_t stream) {
  const float* x     = (const float*)d_in[0];
  const float* Wqkvh = (const float*)d_in[1];
  const float* Wout  = (const float*)d_in[2];
  float* out = (float*)d_out;

  const size_t HD = (size_t)PB * PH * PS * PD;  // 8,388,608 elems = 16.8 MB
  char* wsb = (char*)d_ws;
  __hip_bfloat16* Qp = (__hip_bfloat16*)wsb;   wsb += HD * 2;
  __hip_bfloat16* Kp = (__hip_bfloat16*)wsb;   wsb += HD * 2;
  __hip_bfloat16* Vp = (__hip_bfloat16*)wsb;   wsb += HD * 2;
  __hip_bfloat16* Vtp = (__hip_bfloat16*)wsb;  wsb += HD * 2;
  __hip_bfloat16* xb = (__hip_bfloat16*)wsb;   wsb += (size_t)PM * PE * 2;  // also attn out
  __hip_bfloat16* Wq_t = (__hip_bfloat16*)wsb; wsb += (size_t)3 * PE * PE * 2;
  __hip_bfloat16* Wout_t = (__hip_bfloat16*)wsb; wsb += (size_t)PE * PE * 2;
  float* hgbuf = (float*)wsb;                  wsb += (size_t)PB * PH * PS * 4;
  float* csum = (float*)wsb;

  // 0) gate head + fused x->bf16 cast; weight transposes
  hg_from_x<<<PM, 256, 0, stream>>>(x, Wqkvh, hgbuf, xb);
  transpose_cast<<<dim3(3 * PE / 32, PE / 32), 256, 0, stream>>>(Wqkvh, Wq_t, PN_PROJ, PE, 0);
  transpose_cast<<<dim3(PE / 32, PE / 32), 256, 0, stream>>>(Wout, Wout_t, PE, PE, 0);

  // 1) QKV GEMM -> packed Qp/Kp/Vp[bh][s][d]; 128x384 (1 head/tile),
  //    grid 512 = 2 exact rounds (R9-proven schedule)
  gemm_qkv<<<dim3((PM / 128) * PH), 512, 0, stream>>>(xb, Wq_t, Qp, Kp, Vp, PE, PH);

  // 2) causal weighted cumsum on packed Kp (coalesced), pre-scaled
  kc_pass1<<<PB * PH * 16, 128, 0, stream>>>(Kp, hgbuf, csum);
  kc_pass2<<<PB * PH * 16, 128, 0, stream>>>(Kp, hgbuf, csum);

  // 3) V^T pack + MFMA flash attention -> xb (as O, layout (b,s,h*d))
  vt_pack<<<PB * PH * 32, 256, 0, stream>>>(Vp, Vtp);
  __hip_bfloat16* Ob = xb;
  attn_mfma<<<PB * PH * 8, 256, 0, stream>>>(Qp, Kp, Vtp, Ob);

  // 4) out = Oattn @ W_out (fp32 out) — 3-slot single-barrier, grid 256
  gemm_cs3<128, 256, 2, 4, float>
      <<<dim3((PM / 128) * (PE / 256)), 512, 0, stream>>>(
          Ob, Wout_t, out, PE, PE, PE, PE, PE / 256);
}